// Round 5
// baseline (277.377 us; speedup 1.0000x reference)
//
#include <hip/hip_runtime.h>

#define HW 1024
#define TSTEPS 256
#define SIZE_NORM 5.65685424949238019521f

#define REP16(M)  M(0) M(1) M(2) M(3) M(4) M(5) M(6) M(7) M(8) M(9) M(10) M(11) M(12) M(13) M(14) M(15)
#define REP16D(M) M(15) M(14) M(13) M(12) M(11) M(10) M(9) M(8) M(7) M(6) M(5) M(4) M(3) M(2) M(1) M(0)

__device__ __forceinline__ unsigned umax2(unsigned a, unsigned b) { return a > b ? a : b; }
__device__ __forceinline__ unsigned umax3(unsigned a, unsigned b, unsigned c) {
    return umax2(umax2(a, b), c);   // v_max3_u32
}

// bit-identical to all passing rounds
__device__ __forceinline__ float e_of(float g, float h) {
    float f = 0.5f * g + 0.5f * h;
    return expf(-f / SIZE_NORM);
}

#define DPP_MAX(v, ctrl)                                                                     \
    do {                                                                                     \
        unsigned _o = (unsigned)__builtin_amdgcn_mov_dpp((int)(v), (ctrl), 0xF, 0xF, false); \
        (v) = umax2((v), _o);                                                                \
    } while (0)

__launch_bounds__(64, 1)
__global__ void astar_kernel(const float* __restrict__ cost,
                             const float* __restrict__ start,
                             const float* __restrict__ goal,
                             const float* __restrict__ obst,
                             float* __restrict__ out) {
    __shared__ int   ls_par[HW];
    __shared__ unsigned char ls_m[HW];

    const int b    = blockIdx.x;
    const int lane = threadIdx.x;            // 0..63
    const float* costb  = cost  + b * HW;
    const float* startb = start + b * HW;
    const float* goalb  = goal  + b * HW;
    const float* obstb  = obst  + b * HW;

    // ---- named per-lane state: NO arrays anywhere -> no alloca -> no scratch ----
#define DECL_STATE(K) float cst##K, h##K, g##K; unsigned e##K;
    REP16(DECL_STATE)
#undef DECL_STATE
    unsigned openm = 0, histm = 0, obstm = 0, goalm = 0;

#define LOADK(K) { int c = (K)*64 + lane;                                  \
        cst##K = costb[c]; g##K = 0.0f;                                    \
        openm |= (startb[c] > 0.5f ? 1u : 0u) << (K);                      \
        obstm |= (obstb[c]  > 0.5f ? 1u : 0u) << (K);                      \
        goalm |= (goalb[c]  > 0.5f ? 1u : 0u) << (K); }
    REP16(LOADK)
#undef LOADK

    int gidx = 0;
#define GOALK(K) { unsigned long long m = __ballot((goalm >> (K)) & 1u);   \
        if (m) gidx = (K)*64 + (int)(__ffsll(m) - 1); }
    REP16D(GOALK)
#undef GOALK

    const float gi = (float)(gidx >> 5), gj = (float)(gidx & 31);
#define HINITK(K) { int c = (K)*64 + lane;                                 \
        float ci = (float)(c >> 5), cj = (float)(c & 31);                  \
        float dx = fabsf(ci - gi), dy = fabsf(cj - gj);                    \
        float hc = (dx + dy) - fminf(dx, dy);                              \
        float euc = sqrtf(dx * dx + dy * dy);                              \
        float heur = __fadd_rn(hc, __fmul_rn(0.001f, euc));                \
        h##K = __fadd_rn(heur, cst##K);                                    \
        e##K = ((openm >> (K)) & 1u) ? __float_as_uint(e_of(0.0f, h##K)) : 0u; \
        ls_par[c] = gidx; }
    REP16(HINITK)
#undef HINITK

    // ---- main scan: 256 steps; pure VGPR/SGPR chain, LDS write-only ----
    for (int step = 0; step < TSTEPS; ++step) {
        unsigned m0 = umax3(e0,  e1,  e2);
        unsigned m1 = umax3(e3,  e4,  e5);
        unsigned m2 = umax3(e6,  e7,  e8);
        unsigned m3 = umax3(e9,  e10, e11);
        unsigned m4 = umax3(e12, e13, e14);
        unsigned lm = umax2(umax3(m0, m1, m2), umax3(m3, m4, e15));

        DPP_MAX(lm, 0xB1);    // quad_perm xor1
        DPP_MAX(lm, 0x4E);    // quad_perm xor2
        DPP_MAX(lm, 0x141);   // row_half_mirror
        DPP_MAX(lm, 0x128);   // row_ror:8
        unsigned r0 = (unsigned)__builtin_amdgcn_readlane((int)lm, 0);
        unsigned r1 = (unsigned)__builtin_amdgcn_readlane((int)lm, 16);
        unsigned r2 = (unsigned)__builtin_amdgcn_readlane((int)lm, 32);
        unsigned r3 = (unsigned)__builtin_amdgcn_readlane((int)lm, 48);
        unsigned gmax = umax2(umax2(r0, r1), umax2(r2, r3));

        // first (min-index) matching cell; descending so lowest K wins
        int s_sel = 0;
#define BALK(K) { unsigned long long mm = __ballot(e##K == gmax);          \
        if (mm) s_sel = (K)*64 + (int)(__ffsll(mm) - 1); }
        REP16D(BALK)
#undef BALK
        s_sel = __builtin_amdgcn_readfirstlane(s_sel);   // provably uniform -> SALU

        const int  k_s = s_sel >> 6, lane_s = s_sel & 63;
        const int  si  = s_sel >> 5, sj = s_sel & 31;
        const bool unsolved = (s_sel != gidx);

        // gval = g[s] + cost[s] via uniform switch + readlane (no arrays)
        int g_b, c_b;
        switch (k_s) {
#define RLC(K) case K:                                                         \
            g_b = __builtin_amdgcn_readlane(__float_as_int(g##K),   lane_s);   \
            c_b = __builtin_amdgcn_readlane(__float_as_int(cst##K), lane_s);   \
            break;
            RLC(0)  RLC(1)  RLC(2)  RLC(3)  RLC(4)  RLC(5)  RLC(6)  RLC(7)
            RLC(8)  RLC(9)  RLC(10) RLC(11) RLC(12) RLC(13) RLC(14)
#undef RLC
            default:
                g_b = __builtin_amdgcn_readlane(__float_as_int(g15),   lane_s);
                c_b = __builtin_amdgcn_readlane(__float_as_int(cst15), lane_s);
                break;
        }
        const float gval = __int_as_float(g_b) + __int_as_float(c_b);

        const int k0 = (si > 0  ? si - 1 : 0)  >> 1;
        const int k1 = (si < 31 ? si + 1 : 31) >> 1;

#define UPDK(K) if ((K) >= k0 && (K) <= k1) {                                  \
            const int row = ((K) << 1) + (lane >> 5);                          \
            const int col = lane & 31;                                         \
            const int di = row - si, dj = col - sj;                            \
            bool nb = ((unsigned)(di + 1) <= 2u) && ((unsigned)(dj + 1) <= 2u) \
                      && ((di | dj) != 0) && ((obstm >> (K)) & 1u);            \
            bool op = (openm >> (K)) & 1u;                                     \
            bool hs = (histm >> (K)) & 1u;                                     \
            bool sel = nb && ((!op && !hs) || (op && (gval < g##K)));          \
            if (sel) {                                                         \
                g##K = gval;                                                   \
                openm |= 1u << (K);                                            \
                e##K = __float_as_uint(e_of(gval, h##K));                      \
                ls_par[(K)*64 + lane] = s_sel;                                 \
            }                                                                  \
            if ((K) == k_s && lane == lane_s) {                                \
                histm |= 1u << (K);                                            \
                if (unsolved) { openm &= ~(1u << (K)); e##K = 0u; }            \
            } }
        REP16(UPDK)
#undef UPDK
    }

    // ---- backtrack via pointer doubling (named temps, no arrays) ----
#define MINITK(K) { int c = (K)*64 + lane; ls_m[c] = (c == gidx) ? 1 : 0; }
    REP16(MINITK)
#undef MINITK
    __syncthreads();
    int A0 = ls_par[gidx];
    if (lane == 0) ls_m[A0] = 1;
    __syncthreads();

    for (int j = 0; j < 8; ++j) {            // 2^8 = 256 = TSTEPS
#define DECLBT(K) int pk##K, pp##K;
        REP16(DECLBT)
#undef DECLBT
        unsigned mk = 0;
#define BT1(K) pk##K = ls_par[(K)*64 + lane];
        REP16(BT1)
#undef BT1
#define BT2(K) pp##K = ls_par[pk##K];
        REP16(BT2)
#undef BT2
#define BT3(K) mk |= (unsigned)ls_m[(K)*64 + lane] << (K);
        REP16(BT3)
#undef BT3
        __syncthreads();
#define BT4(K) if ((mk >> (K)) & 1u) ls_m[pk##K] = 1;
        REP16(BT4)
#undef BT4
#define BT5(K) ls_par[(K)*64 + lane] = pp##K;
        REP16(BT5)
#undef BT5
        __syncthreads();
    }

    // ---- outputs: [histories | path], f32 0/1 ----
    float* hout = out + (size_t)b * HW;
    float* pout = out + (size_t)gridDim.x * HW + (size_t)b * HW;
#define OUTK(K) { int c = (K)*64 + lane;                                   \
        hout[c] = (float)((histm >> (K)) & 1u);                            \
        pout[c] = (float)ls_m[c]; }
    REP16(OUTK)
#undef OUTK
}

extern "C" void kernel_launch(void* const* d_in, const int* in_sizes, int n_in,
                              void* d_out, int out_size, void* d_ws, size_t ws_size,
                              hipStream_t stream) {
    (void)n_in; (void)d_ws; (void)ws_size; (void)out_size;
    const float* cost  = (const float*)d_in[0];
    const float* start = (const float*)d_in[1];
    const float* goal  = (const float*)d_in[2];
    const float* obst  = (const float*)d_in[3];
    float* out = (float*)d_out;
    const int nb = in_sizes[0] / HW;
    astar_kernel<<<dim3(nb), dim3(64), 0, stream>>>(cost, start, goal, obst, out);
}